// Round 7
// baseline (47.201 us; speedup 1.0000x reference)
//
#include <hip/hip_runtime.h>
#include <hip/hip_bf16.h>

// Lovasz-Softmax loss, B=8, N=262144 (2^18), C=21, ignore_index=0.
// R7: R5 base (42.4us known-good) + ONE change: K1 processes 4 consecutive
// pixels/thread so the 84B/px logit reads become 21 aligned dwordx4 loads
// per 4-pixel group (group byte base = tid*336, 16B-aligned) instead of
// 21 address-divergent dword loads per pixel. Labels via int4.
// R6 lesson: LDS-atomic contention was NOT the bottleneck (BANK_CONFLICT=0);
// HB=256 restored, 2 replicas, separate K2/K3 (no atomic tail).

#define B_DIM 8
#define N_DIM 262144          // 2^18
#define NCLS 20               // classes 1..20
#define HB 256                // buckets
#define PX_PER_BLK 4096       // K1: 512 threads x 8 pixels (2 groups of 4)
#define BLKS_PER_B 64         // 262144 / 4096
#define NBLK1 (B_DIM * BLKS_PER_B)   // 512
#define HSLOT (NCLS * HB)     // 5120 u32 per histogram (un-skewed)
#define RSTRIDE (HSLOT + 1)   // replica stride (+1 u32 bank skew)

// ---------------------------------------------------------------------------
// Kernel 1: softmax + error bucketing -> per-block packed histograms.
// partial[blk][c-1][h] u32: lo16 = bg count, hi16 = fg count (<=4096 each).
// 2 LDS replicas split by half-wave.
// ---------------------------------------------------------------------------
__global__ __launch_bounds__(512) void lovasz_hist1_kernel(
    const float* __restrict__ logits, const int* __restrict__ labels,
    unsigned* __restrict__ partials) {
  __shared__ unsigned hist[2 * RSTRIDE];
  const int tid = threadIdx.x;

  for (int i = tid; i < 2 * RSTRIDE; i += 512) hist[i] = 0;
  __syncthreads();

  unsigned* myh = hist + ((tid >> 5) & 1) * RSTRIDE;
  const size_t base = (size_t)blockIdx.x * PX_PER_BLK;

  #pragma unroll 1
  for (int j = 0; j < 2; ++j) {
    const size_t p0 = base + (size_t)tid * 4 + (size_t)j * 2048;
    const int4 lab4 = *(const int4*)(labels + p0);
    // 4 pixels * 21 floats = 84 floats = 21 float4, base byte = p0*84,
    // p0 % 4 == 0 -> 336-byte multiple -> 16B aligned.
    const float4* lp4 = (const float4*)(logits + p0 * 21);
    float4 f[21];
    #pragma unroll
    for (int k = 0; k < 21; ++k) f[k] = lp4[k];
    const float* ff = (const float*)f;

    #pragma unroll
    for (int q = 0; q < 4; ++q) {
      const int lab = (&lab4.x)[q];
      float ex[21];
      float denom = 0.f;
      #pragma unroll
      for (int c = 0; c < 21; ++c) {
        ex[c] = __expf(ff[q * 21 + c]);
        denom += ex[c];
      }
      const float inv = 1.0f / denom;
      if (lab != 0) {
        #pragma unroll
        for (int c = 1; c <= NCLS; ++c) {
          const float pc = ex[c] * inv;
          const bool fg = (lab == c);
          const float e = fg ? (1.0f - pc) : pc;     // in (0,1)
          int h = (int)(e * (float)HB);
          h = h < (HB - 1) ? h : (HB - 1);
          atomicAdd(&myh[(c - 1) * HB + h], fg ? 0x10000u : 1u);
        }
      }
    }
  }
  __syncthreads();

  unsigned* outp = partials + (size_t)blockIdx.x * HSLOT;
  for (int i = tid; i < HSLOT; i += 512)
    outp[i] = hist[i] + hist[i + RSTRIDE];
}

// ---------------------------------------------------------------------------
// Kernel 2: one block (256 thr) per (b, class) row. Merge 64 block-partials,
// descending scan over 256 buckets, closed-form Lovasz contribution.
// Entering bucket with k fg / m bg already seen (higher-error buckets), K total:
//   fg: term += n1*e/(K+m);  k += n1;
//   bg: term += (K-k)*e*n0/((K+m)*(K+m+n0));  m += n0;
// Rows with ci==0 publish validCount[b].
// ---------------------------------------------------------------------------
__global__ __launch_bounds__(256) void lovasz_scan_kernel(
    const unsigned* __restrict__ partials, float* __restrict__ terms,
    unsigned* __restrict__ validCount) {
  __shared__ unsigned ts1[256];
  __shared__ unsigned ts0[256];
  __shared__ float redf[256];
  __shared__ int redi[256];

  const int tid = threadIdx.x;                 // owns bucket h = tid
  const int row = blockIdx.x;                  // b*20 + ci
  const int b = row / NCLS;
  const int ci = row % NCLS;

  // Sum this row's bucket across the batch's 64 block-partials (unpack before
  // summing: packed lo-fields would overflow u16).
  unsigned lo = 0, hi = 0;
  const unsigned* pp = partials + (size_t)(b * BLKS_PER_B) * HSLOT + ci * HB + tid;
  #pragma unroll 8
  for (int blk = 0; blk < BLKS_PER_B; ++blk) {
    const unsigned v = pp[(size_t)blk * HSLOT];
    lo += v & 0xFFFFu;
    hi += v >> 16;
  }
  // n0 = lo (bg), n1 = hi (fg) for bucket tid.

  const int r = 255 - tid;                     // descending rank
  ts1[r] = hi; ts0[r] = lo;
  __syncthreads();

  // Inclusive Hillis-Steele scan over descending rank.
  for (int off = 1; off < 256; off <<= 1) {
    unsigned a1 = 0, a0 = 0;
    if (r >= off) { a1 = ts1[r - off]; a0 = ts0[r - off]; }
    __syncthreads();
    ts1[r] += a1; ts0[r] += a0;
    __syncthreads();
  }
  const unsigned K = ts1[255];
  const unsigned V = K + ts0[255];
  if (tid == 0 && ci == 0) validCount[b] = V;

  float term = 0.f;
  if (K > 0) {
    unsigned k = ts1[r] - hi;                  // fg seen before my bucket
    const unsigned m = ts0[r] - lo;            // bg seen before my bucket
    const float e = ((float)tid + 0.5f) * (1.0f / (float)HB);
    if (hi) term += (float)hi * e / (float)(K + m);
    k += hi;
    if (lo) term += (float)(K - k) * e *
                    ((float)lo / ((float)(K + m) * (float)(K + m + lo)));
    redf[tid] = term;
    __syncthreads();
  } else {
    // Degenerate: no fg -> grad = [1,0,...] -> term = max error midpoint.
    redi[tid] = (lo | hi) ? tid : -1;
    redf[tid] = 0.f;
    __syncthreads();
    for (int off = 128; off > 0; off >>= 1) {
      if (tid < off) redi[tid] = redi[tid] > redi[tid + off] ? redi[tid] : redi[tid + off];
      __syncthreads();
    }
    if (tid == 0 && redi[0] >= 0)
      redf[0] = ((float)redi[0] + 0.5f) * (1.0f / (float)HB);
    __syncthreads();
  }

  for (int off = 128; off > 0; off >>= 1) {
    if (tid < off) redf[tid] += redf[tid + off];
    __syncthreads();
  }
  if (tid == 0) terms[row] = redf[0];
}

// ---------------------------------------------------------------------------
// Kernel 3: include-mask + final fixed-order reduction -> scalar loss.
// ---------------------------------------------------------------------------
__global__ __launch_bounds__(256) void lovasz_final_kernel(
    const float* __restrict__ terms, const unsigned* __restrict__ validCount,
    float* __restrict__ out) {
  __shared__ float red[256];
  const int t = threadIdx.x;
  float v = 0.f;
  if (t < B_DIM * NCLS) {
    const int b = t / NCLS;
    if (validCount[b] >= 2) v = terms[t];
  }
  red[t] = v;
  __syncthreads();
  for (int off = 128; off > 0; off >>= 1) {
    if (t < off) red[t] += red[t + off];
    __syncthreads();
  }
  if (t == 0) {
    int cnt = 0;
    #pragma unroll
    for (int b = 0; b < B_DIM; ++b) cnt += (validCount[b] >= 2) ? 1 : 0;
    const int count = cnt * NCLS;
    out[0] = red[0] / (float)(count > 0 ? count : 1);
  }
}

extern "C" void kernel_launch(void* const* d_in, const int* in_sizes, int n_in,
                              void* d_out, int out_size, void* d_ws, size_t ws_size,
                              hipStream_t stream) {
  const float* logits = (const float*)d_in[0];
  const int* labels = (const int*)d_in[1];
  float* out = (float*)d_out;

  char* ws = (char*)d_ws;
  unsigned* validCount = (unsigned*)ws;              // 8 * u32 (written by K2)
  float* terms = (float*)(ws + 64);                  // 160 * f32
  unsigned* partials = (unsigned*)(ws + 1024);       // 512 * 5120 u32 = 10.5 MB

  lovasz_hist1_kernel<<<NBLK1, 512, 0, stream>>>(logits, labels, partials);
  lovasz_scan_kernel<<<B_DIM * NCLS, 256, 0, stream>>>(partials, terms, validCount);
  lovasz_final_kernel<<<1, 256, 0, stream>>>(terms, validCount, out);
}

// Round 8
// 42.282 us; speedup vs baseline: 1.1164x; 1.1164x over previous
//
#include <hip/hip_runtime.h>
#include <hip/hip_bf16.h>

// Lovasz-Softmax loss, B=8, N=262144 (2^18), C=21, ignore_index=0.
// R8: R5 base (42.4us known-good; K1/K3 verbatim). ONE change: K2 merge
// rewritten for latency hiding — 512 thr, 8 independent uint4 loads/thread
// (coalesced 16B/lane across the partials stride), 8-group LDS reduce, then
// the same 256-bucket descending scan + closed-form Lovasz term.
// Lessons: R6 (LDS-atomic contention) and R7 (dwordx4 staging) both refuted;
// K1 ~35us = ~5.6 TB/s effective is near the read-stream ceiling.

#define B_DIM 8
#define N_DIM 262144          // 2^18
#define NCLS 20               // classes 1..20
#define HB 256                // buckets
#define PX_PER_BLK 4096       // K1: 512 threads x 8 pixels
#define BLKS_PER_B 64         // 262144 / 4096
#define NBLK1 (B_DIM * BLKS_PER_B)   // 512
#define HSLOT (NCLS * HB)     // 5120 u32 per histogram (un-skewed)
#define RSTRIDE (HSLOT + 1)   // replica stride (+1 u32 bank skew)

// ---------------------------------------------------------------------------
// Kernel 1: softmax + error bucketing -> per-block packed histograms.
// partial[blk][c-1][h] u32: lo16 = bg count, hi16 = fg count (<=4096 each).
// 2 LDS replicas split by half-wave. (R5 verbatim.)
// ---------------------------------------------------------------------------
__global__ __launch_bounds__(512) void lovasz_hist1_kernel(
    const float* __restrict__ logits, const int* __restrict__ labels,
    unsigned* __restrict__ partials) {
  __shared__ unsigned hist[2 * RSTRIDE];
  const int tid = threadIdx.x;

  for (int i = tid; i < 2 * RSTRIDE; i += 512) hist[i] = 0;
  __syncthreads();

  unsigned* myh = hist + ((tid >> 5) & 1) * RSTRIDE;
  const size_t base = (size_t)blockIdx.x * PX_PER_BLK;

  #pragma unroll
  for (int j = 0; j < 8; ++j) {
    const size_t p = base + tid + j * 512;
    const int lab = labels[p];
    const float* lp = logits + p * 21;
    float ex[21];
    float denom = 0.f;
    #pragma unroll
    for (int c = 0; c < 21; ++c) {
      ex[c] = __expf(lp[c]);
      denom += ex[c];
    }
    const float inv = 1.0f / denom;
    if (lab != 0) {
      #pragma unroll
      for (int c = 1; c <= NCLS; ++c) {
        const float pc = ex[c] * inv;
        const bool fg = (lab == c);
        const float e = fg ? (1.0f - pc) : pc;     // in (0,1)
        int h = (int)(e * (float)HB);
        h = h < (HB - 1) ? h : (HB - 1);
        atomicAdd(&myh[(c - 1) * HB + h], fg ? 0x10000u : 1u);
      }
    }
  }
  __syncthreads();

  unsigned* outp = partials + (size_t)blockIdx.x * HSLOT;
  for (int i = tid; i < HSLOT; i += 512)
    outp[i] = hist[i] + hist[i + RSTRIDE];
}

// ---------------------------------------------------------------------------
// Kernel 2: one block (512 thr) per (b, class) row.
// Merge: thread (g=tid>>6, l=tid&63) owns buckets [4l,4l+4) and accumulates
// partials g, g+8, ..., g+56 via 8 fully-unrolled uint4 loads (independent,
// coalesced 16B/lane). 8-group LDS reduce -> per-bucket (bg,fg) counts.
// Then descending 256-bucket scan + closed-form Lovasz term (guards: first
// 256 threads active, barriers executed by all).
//   fg: term += n1*e/(K+m);  k += n1;
//   bg: term += (K-k)*e*n0/((K+m)*(K+m+n0));  m += n0;
// Rows with ci==0 publish validCount[b].
// ---------------------------------------------------------------------------
__global__ __launch_bounds__(512) void lovasz_scan_kernel(
    const unsigned* __restrict__ partials, float* __restrict__ terms,
    unsigned* __restrict__ validCount) {
  __shared__ unsigned slo[8][HB];
  __shared__ unsigned shi[8][HB];
  __shared__ unsigned ts1[256];
  __shared__ unsigned ts0[256];
  __shared__ float redf[256];
  __shared__ int redi[256];

  const int tid = threadIdx.x;
  const int g = tid >> 6;                      // partial-slice group 0..7
  const int l = tid & 63;                      // owns buckets 4l..4l+3
  const int row = blockIdx.x;                  // b*20 + ci
  const int b = row / NCLS;
  const int ci = row % NCLS;

  const unsigned* base = partials + (size_t)(b * BLKS_PER_B) * HSLOT + ci * HB;
  unsigned lo0 = 0, lo1 = 0, lo2 = 0, lo3 = 0;
  unsigned hi0 = 0, hi1 = 0, hi2 = 0, hi3 = 0;
  #pragma unroll
  for (int s = 0; s < 8; ++s) {
    const uint4 v = *(const uint4*)(base + (size_t)(g + s * 8) * HSLOT + l * 4);
    lo0 += v.x & 0xFFFFu; hi0 += v.x >> 16;
    lo1 += v.y & 0xFFFFu; hi1 += v.y >> 16;
    lo2 += v.z & 0xFFFFu; hi2 += v.z >> 16;
    lo3 += v.w & 0xFFFFu; hi3 += v.w >> 16;
  }
  slo[g][l * 4 + 0] = lo0; shi[g][l * 4 + 0] = hi0;
  slo[g][l * 4 + 1] = lo1; shi[g][l * 4 + 1] = hi1;
  slo[g][l * 4 + 2] = lo2; shi[g][l * 4 + 2] = hi2;
  slo[g][l * 4 + 3] = lo3; shi[g][l * 4 + 3] = hi3;
  __syncthreads();

  // Per-bucket totals: n0 = lo (bg), n1 = hi (fg) for bucket h = tid (<256).
  unsigned lo = 0, hi = 0;
  if (tid < 256) {
    #pragma unroll
    for (int gg = 0; gg < 8; ++gg) { lo += slo[gg][tid]; hi += shi[gg][tid]; }
    const int r = 255 - tid;                   // descending rank
    ts1[r] = hi; ts0[r] = lo;
  }
  __syncthreads();

  // Inclusive Hillis-Steele scan over descending rank (all threads barrier).
  for (int off = 1; off < 256; off <<= 1) {
    unsigned a1 = 0, a0 = 0;
    const int r = 255 - tid;
    const bool act = (tid < 256) && (r >= off);
    if (act) { a1 = ts1[r - off]; a0 = ts0[r - off]; }
    __syncthreads();
    if (act) { ts1[r] += a1; ts0[r] += a0; }
    __syncthreads();
  }
  const unsigned K = ts1[255];
  const unsigned V = K + ts0[255];
  if (tid == 0 && ci == 0) validCount[b] = V;

  if (tid < 256) {
    float term = 0.f;
    if (K > 0) {
      const int r = 255 - tid;
      unsigned k = ts1[r] - hi;                // fg seen before my bucket
      const unsigned m = ts0[r] - lo;          // bg seen before my bucket
      const float e = ((float)tid + 0.5f) * (1.0f / (float)HB);
      if (hi) term += (float)hi * e / (float)(K + m);
      k += hi;
      if (lo) term += (float)(K - k) * e *
                      ((float)lo / ((float)(K + m) * (float)(K + m + lo)));
    }
    redf[tid] = term;
    redi[tid] = (lo | hi) ? tid : -1;
  }
  __syncthreads();

  for (int off = 128; off > 0; off >>= 1) {
    if (tid < off) {
      redf[tid] += redf[tid + off];
      redi[tid] = redi[tid] > redi[tid + off] ? redi[tid] : redi[tid + off];
    }
    __syncthreads();
  }

  if (tid == 0) {
    float t = redf[0];
    if (K == 0)   // degenerate: no fg -> grad=[1,0,...] -> max-error midpoint
      t = (redi[0] >= 0) ? ((float)redi[0] + 0.5f) * (1.0f / (float)HB) : 0.f;
    terms[row] = t;
  }
}

// ---------------------------------------------------------------------------
// Kernel 3: include-mask + final fixed-order reduction -> scalar loss.
// ---------------------------------------------------------------------------
__global__ __launch_bounds__(256) void lovasz_final_kernel(
    const float* __restrict__ terms, const unsigned* __restrict__ validCount,
    float* __restrict__ out) {
  __shared__ float red[256];
  const int t = threadIdx.x;
  float v = 0.f;
  if (t < B_DIM * NCLS) {
    const int b = t / NCLS;
    if (validCount[b] >= 2) v = terms[t];
  }
  red[t] = v;
  __syncthreads();
  for (int off = 128; off > 0; off >>= 1) {
    if (t < off) red[t] += red[t + off];
    __syncthreads();
  }
  if (t == 0) {
    int cnt = 0;
    #pragma unroll
    for (int b = 0; b < B_DIM; ++b) cnt += (validCount[b] >= 2) ? 1 : 0;
    const int count = cnt * NCLS;
    out[0] = red[0] / (float)(count > 0 ? count : 1);
  }
}

extern "C" void kernel_launch(void* const* d_in, const int* in_sizes, int n_in,
                              void* d_out, int out_size, void* d_ws, size_t ws_size,
                              hipStream_t stream) {
  const float* logits = (const float*)d_in[0];
  const int* labels = (const int*)d_in[1];
  float* out = (float*)d_out;

  char* ws = (char*)d_ws;
  unsigned* validCount = (unsigned*)ws;              // 8 * u32 (written by K2)
  float* terms = (float*)(ws + 64);                  // 160 * f32
  unsigned* partials = (unsigned*)(ws + 1024);       // 512 * 5120 u32 = 10.5 MB

  lovasz_hist1_kernel<<<NBLK1, 512, 0, stream>>>(logits, labels, partials);
  lovasz_scan_kernel<<<B_DIM * NCLS, 512, 0, stream>>>(partials, terms, validCount);
  lovasz_final_kernel<<<1, 256, 0, stream>>>(terms, validCount, out);
}